// Round 2
// baseline (9636.130 us; speedup 1.0000x reference)
//
#include <hip/hip_runtime.h>
#include <cstdint>
#include <cstddef>

#define SEQ    64
#define BATCH  32
#define HID    1536
#define VOCAB  32000
#define LAYERS 2
#define MROWS  (SEQ * BATCH)   /* 2048 */
#define HALFV  (VOCAB / 2)     /* 16000 */

typedef __attribute__((ext_vector_type(8))) short bhalf8;   // 8 bf16 in 4 VGPRs
typedef __attribute__((ext_vector_type(4))) float f32x4;

// ---------- bf16 helpers (RNE) ----------
__device__ __forceinline__ float bf2f(unsigned short u) {
  unsigned v = ((unsigned)u) << 16;
  return __builtin_bit_cast(float, v);
}
__device__ __forceinline__ unsigned short f2bf(float f) {
  unsigned u = __builtin_bit_cast(unsigned, f);
  u += 0x7FFFu + ((u >> 16) & 1u);
  return (unsigned short)(u >> 16);
}

__device__ __forceinline__ f32x4 mfma16(bhalf8 a, bhalf8 b, f32x4 c) {
  return __builtin_amdgcn_mfma_f32_16x16x32_bf16(a, b, c, 0, 0, 0);
}

// async global->LDS, 16B per lane (wave-uniform LDS base + lane*16)
__device__ __forceinline__ void gl16(const void* g, void* s) {
  __builtin_amdgcn_global_load_lds(
      (const __attribute__((address_space(1))) unsigned int*)g,
      (__attribute__((address_space(3))) unsigned int*)s, 16, 0, 0);
}

// ---------- transpose+convert W_i*/W_h* (12 matrices 1536x1536) ----------
__global__ __launch_bounds__(256) void trans12_k(
    const float* __restrict__ Wir, const float* __restrict__ Wiu,
    const float* __restrict__ Wic, const float* __restrict__ Whr,
    const float* __restrict__ Whu, const float* __restrict__ Whc,
    unsigned short* __restrict__ WiT_hi, unsigned short* __restrict__ WiT_lo,
    unsigned short* __restrict__ WhT_hi, unsigned short* __restrict__ WhT_lo) {
  __shared__ float tile[32][33];
  int z = blockIdx.z, fam = z >> 1, l = z & 1;
  const float* srcs[6] = {Wir, Wiu, Wic, Whr, Whu, Whc};
  const float* src = srcs[fam] + (size_t)l * HID * HID;
  int gate = (fam < 3) ? fam : fam - 3;
  size_t mo = ((size_t)l * 3 + gate) * HID * HID;
  unsigned short* dhi = ((fam < 3) ? WiT_hi : WhT_hi) + mo;
  unsigned short* dlo = ((fam < 3) ? WiT_lo : WhT_lo) + mo;
  int rb = blockIdx.x * 32, cb = blockIdx.y * 32;
  int tx = threadIdx.x, ty = threadIdx.y;
#pragma unroll
  for (int i = 0; i < 32; i += 8)
    tile[ty + i][tx] = src[(size_t)(rb + ty + i) * HID + cb + tx];
  __syncthreads();
#pragma unroll
  for (int i = 0; i < 32; i += 8) {
    float x = tile[tx][ty + i];
    unsigned short hi = f2bf(x);
    dhi[(size_t)(cb + ty + i) * HID + rb + tx] = hi;
    dlo[(size_t)(cb + ty + i) * HID + rb + tx] = f2bf(x - bf2f(hi));
  }
}

// ---------- transpose+convert a column-slice of W_out (hi only) ----------
__global__ __launch_bounds__(256) void trans_k(
    const float* __restrict__ src, int ldS,
    unsigned short* __restrict__ dhi, int ldD) {
  __shared__ float tile[32][33];
  int rb = blockIdx.x * 32, cb = blockIdx.y * 32;
  int tx = threadIdx.x, ty = threadIdx.y;
#pragma unroll
  for (int i = 0; i < 32; i += 8)
    tile[ty + i][tx] = src[(size_t)(rb + ty + i) * ldS + cb + tx];
  __syncthreads();
#pragma unroll
  for (int i = 0; i < 32; i += 8) {
    float x = tile[tx][ty + i];
    dhi[(size_t)(cb + ty + i) * ldD + rb + tx] = f2bf(x);
  }
}

// ---------- embedding lookup: X0 = emb[tok]*sqrt(E), split to hi/lo ----------
__global__ __launch_bounds__(256) void embed_k(
    const int* __restrict__ tok, const float* __restrict__ emb,
    unsigned short* __restrict__ Xhi, unsigned short* __restrict__ Xlo) {
  int row = blockIdx.x;                  // 0..2047 == t*32+b
  int t = tok[row];
  const float scale = 39.191835884530850f;  // sqrt(1536)
  const float* src = emb + (size_t)t * HID;
#pragma unroll
  for (int e = threadIdx.x; e < HID; e += 256) {
    float x = src[e] * scale;
    unsigned short hi = f2bf(x);
    Xhi[(size_t)row * HID + e] = hi;
    Xlo[(size_t)row * HID + e] = f2bf(x - bf2f(hi));
  }
}

// ---------- h0 init from `hidden` input ----------
__global__ __launch_bounds__(256) void hinit_k(
    const float* __restrict__ h, unsigned short* __restrict__ hhi,
    unsigned short* __restrict__ hlo) {
  int i = blockIdx.x * 256 + threadIdx.x;  // < 32*1536
  float x = h[i];
  unsigned short hi = f2bf(x);
  hhi[i] = hi;
  hlo[i] = f2bf(x - bf2f(hi));
}

// ---------- split-bf16 GEMM: C = Ahi/lo [M,K] x (Bhi/lo)^T [N,K] + bias ----------
// tile 128x64, BK=32, 4 waves (2x2), per-wave frags 4x2
__global__ __launch_bounds__(256) void gemm_split_k(
    const unsigned short* __restrict__ Ahi, const unsigned short* __restrict__ Alo,
    const unsigned short* __restrict__ Bhi, const unsigned short* __restrict__ Blo,
    const float* __restrict__ bias, float* __restrict__ C, int K, int ldC) {
  __shared__ unsigned short lds[12288];  // Ah 4096 | Al 4096 | Bh 2048 | Bl 2048
  unsigned short* Ah = lds;
  unsigned short* Al = lds + 4096;
  unsigned short* Bh = lds + 8192;
  unsigned short* Bl = lds + 10240;
  int m0 = blockIdx.x * 128, n0 = blockIdx.y * 64;
  int tid = threadIdx.x, wave = tid >> 6, lane = tid & 63;
  int lg = lane >> 4, lr = lane & 15;
  int wr = (wave >> 1) * 64, wc = (wave & 1) * 32;
  f32x4 acc[4][2] = {};
  int e0 = tid * 8, r0 = e0 >> 5, kk0 = e0 & 31;
  int e1 = (256 + tid) * 8, r1 = e1 >> 5, kk1 = e1 & 31;
  for (int k0 = 0; k0 < K; k0 += 32) {
    gl16(&Ahi[(size_t)(m0 + r0) * K + k0 + kk0], &Ah[e0]);
    gl16(&Ahi[(size_t)(m0 + r1) * K + k0 + kk1], &Ah[e1]);
    gl16(&Alo[(size_t)(m0 + r0) * K + k0 + kk0], &Al[e0]);
    gl16(&Alo[(size_t)(m0 + r1) * K + k0 + kk1], &Al[e1]);
    gl16(&Bhi[(size_t)(n0 + r0) * K + k0 + kk0], &Bh[e0]);
    gl16(&Blo[(size_t)(n0 + r0) * K + k0 + kk0], &Bl[e0]);
    __syncthreads();
    bhalf8 a_h[4], a_l[4], b_h[2], b_l[2];
#pragma unroll
    for (int f = 0; f < 4; ++f) {
      a_h[f] = *(const bhalf8*)&Ah[(wr + f * 16 + lr) * 32 + lg * 8];
      a_l[f] = *(const bhalf8*)&Al[(wr + f * 16 + lr) * 32 + lg * 8];
    }
#pragma unroll
    for (int f = 0; f < 2; ++f) {
      b_h[f] = *(const bhalf8*)&Bh[(wc + f * 16 + lr) * 32 + lg * 8];
      b_l[f] = *(const bhalf8*)&Bl[(wc + f * 16 + lr) * 32 + lg * 8];
    }
#pragma unroll
    for (int i = 0; i < 4; ++i)
#pragma unroll
      for (int j = 0; j < 2; ++j) {
        acc[i][j] = mfma16(a_h[i], b_h[j], acc[i][j]);
        acc[i][j] = mfma16(a_h[i], b_l[j], acc[i][j]);
        acc[i][j] = mfma16(a_l[i], b_h[j], acc[i][j]);
      }
    __syncthreads();
  }
#pragma unroll
  for (int j = 0; j < 2; ++j) {
    int col = n0 + wc + j * 16 + lr;
    float bv = bias[col];
#pragma unroll
    for (int i = 0; i < 4; ++i)
#pragma unroll
      for (int r = 0; r < 4; ++r) {
        int row = m0 + wr + i * 16 + lg * 4 + r;
        C[(size_t)row * ldC + col] = acc[i][j][r] + bv;
      }
  }
}

// ---------- plain bf16 GEMM (final logits): tile 128x128, frags 4x4 ----------
__global__ __launch_bounds__(256) void gemm_plain_k(
    const unsigned short* __restrict__ A, const unsigned short* __restrict__ BT,
    const float* __restrict__ bias, float* __restrict__ C, int K, int ldC) {
  __shared__ unsigned short lds[8192];  // Ah 4096 | Bh 4096
  unsigned short* Ah = lds;
  unsigned short* Bh = lds + 4096;
  int m0 = blockIdx.x * 128, n0 = blockIdx.y * 128;
  int tid = threadIdx.x, wave = tid >> 6, lane = tid & 63;
  int lg = lane >> 4, lr = lane & 15;
  int wr = (wave >> 1) * 64, wc = (wave & 1) * 64;
  f32x4 acc[4][4] = {};
  int e0 = tid * 8, r0 = e0 >> 5, kk0 = e0 & 31;
  int e1 = (256 + tid) * 8, r1 = e1 >> 5, kk1 = e1 & 31;
  for (int k0 = 0; k0 < K; k0 += 32) {
    gl16(&A[(size_t)(m0 + r0) * K + k0 + kk0], &Ah[e0]);
    gl16(&A[(size_t)(m0 + r1) * K + k0 + kk1], &Ah[e1]);
    gl16(&BT[(size_t)(n0 + r0) * K + k0 + kk0], &Bh[e0]);
    gl16(&BT[(size_t)(n0 + r1) * K + k0 + kk1], &Bh[e1]);
    __syncthreads();
    bhalf8 a[4], b[4];
#pragma unroll
    for (int f = 0; f < 4; ++f) {
      a[f] = *(const bhalf8*)&Ah[(wr + f * 16 + lr) * 32 + lg * 8];
      b[f] = *(const bhalf8*)&Bh[(wc + f * 16 + lr) * 32 + lg * 8];
    }
#pragma unroll
    for (int i = 0; i < 4; ++i)
#pragma unroll
      for (int j = 0; j < 4; ++j)
        acc[i][j] = mfma16(a[i], b[j], acc[i][j]);
    __syncthreads();
  }
#pragma unroll
  for (int j = 0; j < 4; ++j) {
    int col = n0 + wc + j * 16 + lr;
    float bv = bias[col];
#pragma unroll
    for (int i = 0; i < 4; ++i)
#pragma unroll
      for (int r = 0; r < 4; ++r) {
        int row = m0 + wr + i * 16 + lg * 4 + r;
        C[(size_t)row * ldC + col] = acc[i][j][r] + bv;
      }
  }
}

// ---------- one recurrence step (one layer): h@W_h{r,u,c} + gates ----------
// grid = 24 blocks (64 cols each), 4 waves x 16 cols; split-bf16 (3 mfma/term)
__global__ __launch_bounds__(256) void gru_step_k(
    const unsigned short* __restrict__ hp_hi, const unsigned short* __restrict__ hp_lo,
    const unsigned short* __restrict__ WhT_hi, const unsigned short* __restrict__ WhT_lo,
    const float* __restrict__ G,  // [3][2048][1536], rows t*32..
    const float* __restrict__ bhr, const float* __restrict__ bhu,
    const float* __restrict__ bhc,
    unsigned short* __restrict__ Xo_hi, unsigned short* __restrict__ Xo_lo,  // [32][1536]
    float* __restrict__ hfin, int t) {
  int wave = threadIdx.x >> 6, lane = threadIdx.x & 63;
  int lg = lane >> 4, lr = lane & 15;
  int nb = blockIdx.x * 64 + wave * 16;
  f32x4 acc[2][3] = {};
#pragma unroll 2
  for (int k0 = 0; k0 < HID; k0 += 32) {
    bhalf8 ah0 = *(const bhalf8*)&hp_hi[(size_t)(lr)*HID + k0 + lg * 8];
    bhalf8 ah1 = *(const bhalf8*)&hp_hi[(size_t)(16 + lr) * HID + k0 + lg * 8];
    bhalf8 al0 = *(const bhalf8*)&hp_lo[(size_t)(lr)*HID + k0 + lg * 8];
    bhalf8 al1 = *(const bhalf8*)&hp_lo[(size_t)(16 + lr) * HID + k0 + lg * 8];
#pragma unroll
    for (int g = 0; g < 3; ++g) {
      size_t boff = ((size_t)g * HID + nb + lr) * HID + k0 + lg * 8;
      bhalf8 bh = *(const bhalf8*)&WhT_hi[boff];
      bhalf8 bl = *(const bhalf8*)&WhT_lo[boff];
      acc[0][g] = mfma16(ah0, bh, acc[0][g]);
      acc[0][g] = mfma16(ah0, bl, acc[0][g]);
      acc[0][g] = mfma16(al0, bh, acc[0][g]);
      acc[1][g] = mfma16(ah1, bh, acc[1][g]);
      acc[1][g] = mfma16(ah1, bl, acc[1][g]);
      acc[1][g] = mfma16(al1, bh, acc[1][g]);
    }
  }
  int n = nb + lr;
  float brv = bhr[n], buv = bhu[n], bcv = bhc[n];
#pragma unroll
  for (int fm = 0; fm < 2; ++fm)
#pragma unroll
    for (int r = 0; r < 4; ++r) {
      int m = fm * 16 + lg * 4 + r;
      size_t grow = (size_t)t * 32 + m;
      float gr = G[(0 * (size_t)MROWS + grow) * HID + n] + acc[fm][0][r] + brv;
      float gu = G[(1 * (size_t)MROWS + grow) * HID + n] + acc[fm][1][r] + buv;
      float gc = G[(2 * (size_t)MROWS + grow) * HID + n];
      float hcand = acc[fm][2][r] + bcv;
      float rg = 1.f / (1.f + expf(-gr));
      float ug = 1.f / (1.f + expf(-gu));
      float cg = tanhf(gc + rg * hcand);
      float ho = bf2f(hp_hi[(size_t)m * HID + n]) + bf2f(hp_lo[(size_t)m * HID + n]);
      float hn = (1.f - ug) * cg + ug * ho;
      unsigned short hi = f2bf(hn);
      Xo_hi[(size_t)m * HID + n] = hi;
      Xo_lo[(size_t)m * HID + n] = f2bf(hn - bf2f(hi));
      if (hfin) hfin[(size_t)m * HID + n] = hn;
    }
}

// ---------- host ----------
extern "C" void kernel_launch(void* const* d_in, const int* in_sizes, int n_in,
                              void* d_out, int out_size, void* d_ws, size_t ws_size,
                              hipStream_t stream) {
  const int* tok = (const int*)d_in[0];
  const float* hidden = (const float*)d_in[1];
  const float* emb = (const float*)d_in[2];
  const float* W_ir = (const float*)d_in[3];
  const float* b_ir = (const float*)d_in[4];
  const float* W_hr = (const float*)d_in[5];
  const float* b_hr = (const float*)d_in[6];
  const float* W_iu = (const float*)d_in[7];
  const float* b_iu = (const float*)d_in[8];
  const float* W_hu = (const float*)d_in[9];
  const float* b_hu = (const float*)d_in[10];
  const float* W_ic = (const float*)d_in[11];
  const float* b_ic = (const float*)d_in[12];
  const float* W_hc = (const float*)d_in[13];
  const float* b_hc = (const float*)d_in[14];
  const float* W_out = (const float*)d_in[15];
  const float* b_out = (const float*)d_in[16];

  char* p = (char*)d_ws;
  auto carve = [&](size_t n) {
    void* r = (void*)p;
    p += (n + 255) & ~(size_t)255;
    return r;
  };
  const size_t HH = (size_t)HID * HID;
  unsigned short* WiT_hi = (unsigned short*)carve(LAYERS * 3 * HH * 2);
  unsigned short* WiT_lo = (unsigned short*)carve(LAYERS * 3 * HH * 2);
  unsigned short* WhT_hi = (unsigned short*)carve(LAYERS * 3 * HH * 2);
  unsigned short* WhT_lo = (unsigned short*)carve(LAYERS * 3 * HH * 2);
  unsigned short* WoT = (unsigned short*)carve((size_t)HALFV * HID * 2);
  unsigned short* X0_hi = (unsigned short*)carve((size_t)MROWS * HID * 2);
  unsigned short* X0_lo = (unsigned short*)carve((size_t)MROWS * HID * 2);
  unsigned short* Xs_hi = (unsigned short*)carve((size_t)MROWS * HID * 2);
  unsigned short* Xs_lo = (unsigned short*)carve((size_t)MROWS * HID * 2);
  float* G = (float*)carve((size_t)3 * MROWS * HID * 4);
  unsigned short* h0_hi = (unsigned short*)carve((size_t)BATCH * HID * 2);
  unsigned short* h0_lo = (unsigned short*)carve((size_t)BATCH * HID * 2);

  float* out = (float*)d_out;
  float* hfin_base = out + (size_t)MROWS * VOCAB;

  trans12_k<<<dim3(48, 48, 12), dim3(32, 8), 0, stream>>>(
      W_ir, W_iu, W_ic, W_hr, W_hu, W_hc, WiT_hi, WiT_lo, WhT_hi, WhT_lo);
  embed_k<<<MROWS, 256, 0, stream>>>(tok, emb, X0_hi, X0_lo);

  for (int l = 0; l < LAYERS; ++l) {
    const unsigned short* Ahi = (l == 0) ? X0_hi : Xs_hi;
    const unsigned short* Alo = (l == 0) ? X0_lo : Xs_lo;
    const float* bi[3] = {b_ir + l * HID, b_iu + l * HID, b_ic + l * HID};
    for (int g = 0; g < 3; ++g) {
      gemm_split_k<<<dim3(16, 24), 256, 0, stream>>>(
          Ahi, Alo, WiT_hi + ((size_t)l * 3 + g) * HH, WiT_lo + ((size_t)l * 3 + g) * HH,
          bi[g], G + (size_t)g * MROWS * HID, HID, HID);
    }
    hinit_k<<<192, 256, 0, stream>>>(hidden + (size_t)l * BATCH * HID, h0_hi, h0_lo);
    const float* bh_r = b_hr + l * HID;
    const float* bh_u = b_hu + l * HID;
    const float* bh_c = b_hc + l * HID;
    for (int t = 0; t < SEQ; ++t) {
      const unsigned short* hp_hi = (t == 0) ? h0_hi : Xs_hi + (size_t)(t - 1) * BATCH * HID;
      const unsigned short* hp_lo = (t == 0) ? h0_lo : Xs_lo + (size_t)(t - 1) * BATCH * HID;
      gru_step_k<<<24, 256, 0, stream>>>(
          hp_hi, hp_lo, WhT_hi + (size_t)l * 3 * HH, WhT_lo + (size_t)l * 3 * HH,
          G, bh_r, bh_u, bh_c,
          Xs_hi + (size_t)t * BATCH * HID, Xs_lo + (size_t)t * BATCH * HID,
          (t == SEQ - 1) ? (hfin_base + (size_t)l * BATCH * HID) : nullptr, t);
    }
  }

  for (int hf = 0; hf < 2; ++hf) {
    int coffs = hf * HALFV;
    trans_k<<<dim3(48, 500), dim3(32, 8), 0, stream>>>(W_out + coffs, VOCAB, WoT, HID);
    gemm_plain_k<<<dim3(16, 125), 256, 0, stream>>>(
        Xs_hi, WoT, b_out + coffs, out + coffs, HID, VOCAB);
  }
}

// Round 4
// 3016.378 us; speedup vs baseline: 3.1946x; 3.1946x over previous
//
#include <hip/hip_runtime.h>
#include <cstdint>
#include <cstddef>

#define SEQ    64
#define BATCH  32
#define HID    1536
#define VOCAB  32000
#define LAYERS 2
#define MROWS  (SEQ * BATCH)   /* 2048 */
#define HALFV  (VOCAB / 2)     /* 16000 */
#define NBLK   96              /* persistent recurrence blocks */

typedef __attribute__((ext_vector_type(8))) short bhalf8;   // 8 bf16 in 4 VGPRs
typedef __attribute__((ext_vector_type(4))) float f32x4;

// ---------- bf16 helpers (RNE) ----------
__device__ __forceinline__ float bf2f(unsigned short u) {
  unsigned v = ((unsigned)u) << 16;
  return __builtin_bit_cast(float, v);
}
__device__ __forceinline__ unsigned short f2bf(float f) {
  unsigned u = __builtin_bit_cast(unsigned, f);
  u += 0x7FFFu + ((u >> 16) & 1u);
  return (unsigned short)(u >> 16);
}

__device__ __forceinline__ f32x4 mfma16(bhalf8 a, bhalf8 b, f32x4 c) {
  return __builtin_amdgcn_mfma_f32_16x16x32_bf16(a, b, c, 0, 0, 0);
}

// async global->LDS, 16B per lane (wave-uniform LDS base + lane*16)
__device__ __forceinline__ void gl16(const void* g, void* s) {
  __builtin_amdgcn_global_load_lds(
      (const __attribute__((address_space(1))) unsigned int*)g,
      (__attribute__((address_space(3))) unsigned int*)s, 16, 0, 0);
}

// ---------- transpose+convert W_i*/W_h* (12 matrices 1536x1536) ----------
__global__ __launch_bounds__(256) void trans12_k(
    const float* __restrict__ Wir, const float* __restrict__ Wiu,
    const float* __restrict__ Wic, const float* __restrict__ Whr,
    const float* __restrict__ Whu, const float* __restrict__ Whc,
    unsigned short* __restrict__ WiT_hi, unsigned short* __restrict__ WiT_lo,
    unsigned short* __restrict__ WhT_hi, unsigned short* __restrict__ WhT_lo) {
  __shared__ float tile[32][33];
  int z = blockIdx.z, fam = z >> 1, l = z & 1;
  const float* srcs[6] = {Wir, Wiu, Wic, Whr, Whu, Whc};
  const float* src = srcs[fam] + (size_t)l * HID * HID;
  int gate = (fam < 3) ? fam : fam - 3;
  size_t mo = ((size_t)l * 3 + gate) * HID * HID;
  unsigned short* dhi = ((fam < 3) ? WiT_hi : WhT_hi) + mo;
  unsigned short* dlo = ((fam < 3) ? WiT_lo : WhT_lo) + mo;
  int rb = blockIdx.x * 32, cb = blockIdx.y * 32;
  int tx = threadIdx.x, ty = threadIdx.y;
#pragma unroll
  for (int i = 0; i < 32; i += 8)
    tile[ty + i][tx] = src[(size_t)(rb + ty + i) * HID + cb + tx];
  __syncthreads();
#pragma unroll
  for (int i = 0; i < 32; i += 8) {
    float x = tile[tx][ty + i];
    unsigned short hi = f2bf(x);
    dhi[(size_t)(cb + ty + i) * HID + rb + tx] = hi;
    dlo[(size_t)(cb + ty + i) * HID + rb + tx] = f2bf(x - bf2f(hi));
  }
}

// ---------- transpose+convert a column-slice of W_out (hi only) ----------
__global__ __launch_bounds__(256) void trans_k(
    const float* __restrict__ src, int ldS,
    unsigned short* __restrict__ dhi, int ldD) {
  __shared__ float tile[32][33];
  int rb = blockIdx.x * 32, cb = blockIdx.y * 32;
  int tx = threadIdx.x, ty = threadIdx.y;
#pragma unroll
  for (int i = 0; i < 32; i += 8)
    tile[ty + i][tx] = src[(size_t)(rb + ty + i) * ldS + cb + tx];
  __syncthreads();
#pragma unroll
  for (int i = 0; i < 32; i += 8) {
    float x = tile[tx][ty + i];
    dhi[(size_t)(cb + ty + i) * ldD + rb + tx] = f2bf(x);
  }
}

// ---------- embedding lookup: X0 = emb[tok]*sqrt(E), split to hi/lo ----------
__global__ __launch_bounds__(256) void embed_k(
    const int* __restrict__ tok, const float* __restrict__ emb,
    unsigned short* __restrict__ Xhi, unsigned short* __restrict__ Xlo) {
  int row = blockIdx.x;                  // 0..2047 == t*32+b
  int t = tok[row];
  const float scale = 39.191835884530850f;  // sqrt(1536)
  const float* src = emb + (size_t)t * HID;
#pragma unroll
  for (int e = threadIdx.x; e < HID; e += 256) {
    float x = src[e] * scale;
    unsigned short hi = f2bf(x);
    Xhi[(size_t)row * HID + e] = hi;
    Xlo[(size_t)row * HID + e] = f2bf(x - bf2f(hi));
  }
}

// ---------- h0 init: f32 master + hi/lo split ----------
__global__ __launch_bounds__(256) void hinit_k(
    const float* __restrict__ h, unsigned short* __restrict__ hhi,
    unsigned short* __restrict__ hlo, float* __restrict__ hf) {
  int i = blockIdx.x * 256 + threadIdx.x;  // < 32*1536
  float x = h[i];
  hf[i] = x;
  unsigned short hi = f2bf(x);
  hhi[i] = hi;
  hlo[i] = f2bf(x - bf2f(hi));
}

// ---------- split-bf16 GEMM: C = Ahi/lo [M,K] x (Bhi/lo)^T [N,K] + bias ----------
__global__ __launch_bounds__(256) void gemm_split_k(
    const unsigned short* __restrict__ Ahi, const unsigned short* __restrict__ Alo,
    const unsigned short* __restrict__ Bhi, const unsigned short* __restrict__ Blo,
    const float* __restrict__ bias, float* __restrict__ C, int K, int ldC) {
  __shared__ unsigned short lds[12288];  // Ah 4096 | Al 4096 | Bh 2048 | Bl 2048
  unsigned short* Ah = lds;
  unsigned short* Al = lds + 4096;
  unsigned short* Bh = lds + 8192;
  unsigned short* Bl = lds + 10240;
  int m0 = blockIdx.x * 128, n0 = blockIdx.y * 64;
  int tid = threadIdx.x, wave = tid >> 6, lane = tid & 63;
  int lg = lane >> 4, lr = lane & 15;
  int wr = (wave >> 1) * 64, wc = (wave & 1) * 32;
  f32x4 acc[4][2] = {};
  int e0 = tid * 8, r0 = e0 >> 5, kk0 = e0 & 31;
  int e1 = (256 + tid) * 8, r1 = e1 >> 5, kk1 = e1 & 31;
  for (int k0 = 0; k0 < K; k0 += 32) {
    gl16(&Ahi[(size_t)(m0 + r0) * K + k0 + kk0], &Ah[e0]);
    gl16(&Ahi[(size_t)(m0 + r1) * K + k0 + kk1], &Ah[e1]);
    gl16(&Alo[(size_t)(m0 + r0) * K + k0 + kk0], &Al[e0]);
    gl16(&Alo[(size_t)(m0 + r1) * K + k0 + kk1], &Al[e1]);
    gl16(&Bhi[(size_t)(n0 + r0) * K + k0 + kk0], &Bh[e0]);
    gl16(&Blo[(size_t)(n0 + r0) * K + k0 + kk0], &Bl[e0]);
    __syncthreads();
    bhalf8 a_h[4], a_l[4], b_h[2], b_l[2];
#pragma unroll
    for (int f = 0; f < 4; ++f) {
      a_h[f] = *(const bhalf8*)&Ah[(wr + f * 16 + lr) * 32 + lg * 8];
      a_l[f] = *(const bhalf8*)&Al[(wr + f * 16 + lr) * 32 + lg * 8];
    }
#pragma unroll
    for (int f = 0; f < 2; ++f) {
      b_h[f] = *(const bhalf8*)&Bh[(wc + f * 16 + lr) * 32 + lg * 8];
      b_l[f] = *(const bhalf8*)&Bl[(wc + f * 16 + lr) * 32 + lg * 8];
    }
#pragma unroll
    for (int i = 0; i < 4; ++i)
#pragma unroll
      for (int j = 0; j < 2; ++j) {
        acc[i][j] = mfma16(a_h[i], b_h[j], acc[i][j]);
        acc[i][j] = mfma16(a_h[i], b_l[j], acc[i][j]);
        acc[i][j] = mfma16(a_l[i], b_h[j], acc[i][j]);
      }
    __syncthreads();
  }
#pragma unroll
  for (int j = 0; j < 2; ++j) {
    int col = n0 + wc + j * 16 + lr;
    float bv = bias[col];
#pragma unroll
    for (int i = 0; i < 4; ++i)
#pragma unroll
      for (int r = 0; r < 4; ++r) {
        int row = m0 + wr + i * 16 + lg * 4 + r;
        C[(size_t)row * ldC + col] = acc[i][j][r] + bv;
      }
  }
}

// ---------- plain bf16 GEMM (final logits), XCD-swizzled ----------
__global__ __launch_bounds__(256) void gemm_plain_k(
    const unsigned short* __restrict__ A, const unsigned short* __restrict__ BT,
    const float* __restrict__ bias, float* __restrict__ C, int K, int ldC) {
  __shared__ unsigned short lds[8192];  // Ah 4096 | Bh 4096
  unsigned short* Ah = lds;
  unsigned short* Bh = lds + 4096;
  // XCD-aware swizzle (nwg % 8 == 0: bijective)
  int nwg = gridDim.x * gridDim.y;
  int bid = blockIdx.y * gridDim.x + blockIdx.x;
  int cpx = nwg >> 3;
  int swz = (bid & 7) * cpx + (bid >> 3);
  int bx = swz % gridDim.x, by = swz / gridDim.x;
  int m0 = bx * 128, n0 = by * 128;
  int tid = threadIdx.x, wave = tid >> 6, lane = tid & 63;
  int lg = lane >> 4, lr = lane & 15;
  int wr = (wave >> 1) * 64, wc = (wave & 1) * 64;
  f32x4 acc[4][4] = {};
  int e0 = tid * 8, r0 = e0 >> 5, kk0 = e0 & 31;
  int e1 = (256 + tid) * 8, r1 = e1 >> 5, kk1 = e1 & 31;
  for (int k0 = 0; k0 < K; k0 += 32) {
    gl16(&A[(size_t)(m0 + r0) * K + k0 + kk0], &Ah[e0]);
    gl16(&A[(size_t)(m0 + r1) * K + k0 + kk1], &Ah[e1]);
    gl16(&BT[(size_t)(n0 + r0) * K + k0 + kk0], &Bh[e0]);
    gl16(&BT[(size_t)(n0 + r1) * K + k0 + kk1], &Bh[e1]);
    __syncthreads();
    bhalf8 a[4], b[4];
#pragma unroll
    for (int f = 0; f < 4; ++f) {
      a[f] = *(const bhalf8*)&Ah[(wr + f * 16 + lr) * 32 + lg * 8];
      b[f] = *(const bhalf8*)&Bh[(wc + f * 16 + lr) * 32 + lg * 8];
    }
#pragma unroll
    for (int i = 0; i < 4; ++i)
#pragma unroll
      for (int j = 0; j < 4; ++j)
        acc[i][j] = mfma16(a[i], b[j], acc[i][j]);
    __syncthreads();
  }
#pragma unroll
  for (int j = 0; j < 4; ++j) {
    int col = n0 + wc + j * 16 + lr;
    float bv = bias[col];
#pragma unroll
    for (int i = 0; i < 4; ++i)
#pragma unroll
      for (int r = 0; r < 4; ++r) {
        int row = m0 + wr + i * 16 + lg * 4 + r;
        C[(size_t)row * ldC + col] = acc[i][j][r] + bv;
      }
  }
}

// ---------- persistent per-layer recurrence: 64 steps in one launch ----------
// 96 blocks x 512 threads (8 waves). Block owns 16 output cols (ns).
// Wave w owns K-chunk [w*192, w*192+192): holds Wh hi/lo fragments in VGPRs
// (36 bhalf8 = 144 VGPR). Per step: partial MFMA -> LDS -> reduce+gates ->
// write h rows into Xs -> grid barrier (agent-scope atomic + threadfence).
__global__ __launch_bounds__(512, 2) void gru_seq_k(
    const unsigned short* __restrict__ h0_hi, const unsigned short* __restrict__ h0_lo,
    const unsigned short* __restrict__ WhT_hi, const unsigned short* __restrict__ WhT_lo,
    const float* __restrict__ G,
    const float* __restrict__ bhr, const float* __restrict__ bhu,
    const float* __restrict__ bhc,
    unsigned short* __restrict__ Xs_hi, unsigned short* __restrict__ Xs_lo,
    float* __restrict__ hf32,   // [2][32*1536] ping-pong master
    float* __restrict__ hfin,   // final h for this layer
    unsigned* __restrict__ cnt) {
  __shared__ float pacc[8 * 3 * 32 * 17];  // 52 KB, stride-17 padded
  int tid = threadIdx.x;
  int w = tid >> 6, lane = tid & 63;
  int lg = lane >> 4, lr = lane & 15;
  int ns = blockIdx.x * 16;
  int wk = w * 192;

  // ---- preload weights into VGPRs (static indexing only!) ----
  bhalf8 wh[6][3], wl[6][3];
#pragma unroll
  for (int ki = 0; ki < 6; ++ki)
#pragma unroll
    for (int g = 0; g < 3; ++g) {
      size_t off = ((size_t)g * HID + ns + lr) * HID + wk + ki * 32 + lg * 8;
      wh[ki][g] = *(const bhalf8*)&WhT_hi[off];
      wl[ki][g] = *(const bhalf8*)&WhT_lo[off];
    }

  // gate-phase constants (thread -> element (m,n))
  int gm = tid >> 4, gn = tid & 15, gcol = ns + gn;
  float brv = bhr[gcol], buv = bhu[gcol], bcv = bhc[gcol];

  for (int s = 0; s < SEQ; ++s) {
    const unsigned short* Ahi = s ? Xs_hi + (size_t)(s - 1) * BATCH * HID : h0_hi;
    const unsigned short* Alo = s ? Xs_lo + (size_t)(s - 1) * BATCH * HID : h0_lo;
    // ---- phase A: partial GEMM over this wave's K-chunk ----
    f32x4 acc[2][3] = {};
#pragma unroll
    for (int ki = 0; ki < 6; ++ki) {
      int k = wk + ki * 32 + lg * 8;
      bhalf8 ah0 = *(const bhalf8*)&Ahi[(size_t)lr * HID + k];
      bhalf8 ah1 = *(const bhalf8*)&Ahi[(size_t)(16 + lr) * HID + k];
      bhalf8 al0 = *(const bhalf8*)&Alo[(size_t)lr * HID + k];
      bhalf8 al1 = *(const bhalf8*)&Alo[(size_t)(16 + lr) * HID + k];
#pragma unroll
      for (int g = 0; g < 3; ++g) {
        acc[0][g] = mfma16(ah0, wh[ki][g], acc[0][g]);
        acc[0][g] = mfma16(ah0, wl[ki][g], acc[0][g]);
        acc[0][g] = mfma16(al0, wh[ki][g], acc[0][g]);
        acc[1][g] = mfma16(ah1, wh[ki][g], acc[1][g]);
        acc[1][g] = mfma16(ah1, wl[ki][g], acc[1][g]);
        acc[1][g] = mfma16(al1, wh[ki][g], acc[1][g]);
      }
    }
#pragma unroll
    for (int g = 0; g < 3; ++g)
#pragma unroll
      for (int fm = 0; fm < 2; ++fm)
#pragma unroll
        for (int r = 0; r < 4; ++r)
          pacc[((w * 3 + g) * 32 + fm * 16 + lg * 4 + r) * 17 + lr] = acc[fm][g][r];
    __syncthreads();

    // ---- phase B: reduce 8 waves + gates, write h/Xs ----
    {
      float s0 = 0.f, s1 = 0.f, s2 = 0.f;
#pragma unroll
      for (int w2 = 0; w2 < 8; ++w2) {
        s0 += pacc[((w2 * 3 + 0) * 32 + gm) * 17 + gn];
        s1 += pacc[((w2 * 3 + 1) * 32 + gm) * 17 + gn];
        s2 += pacc[((w2 * 3 + 2) * 32 + gm) * 17 + gn];
      }
      size_t grow = (size_t)s * 32 + gm;
      float gr = G[(0 * (size_t)MROWS + grow) * HID + gcol] + s0 + brv;
      float gu = G[(1 * (size_t)MROWS + grow) * HID + gcol] + s1 + buv;
      float gc = G[(2 * (size_t)MROWS + grow) * HID + gcol];
      float hcand = s2 + bcv;
      float rg = 1.f / (1.f + expf(-gr));
      float ug = 1.f / (1.f + expf(-gu));
      float cg = tanhf(gc + rg * hcand);
      int p = s & 1;
      float ho = hf32[(size_t)p * BATCH * HID + (size_t)gm * HID + gcol];
      float hn = (1.f - ug) * cg + ug * ho;
      hf32[(size_t)(p ^ 1) * BATCH * HID + (size_t)gm * HID + gcol] = hn;
      unsigned short hi = f2bf(hn);
      size_t xrow = ((size_t)s * 32 + gm) * HID + gcol;
      Xs_hi[xrow] = hi;
      Xs_lo[xrow] = f2bf(hn - bf2f(hi));
      if (s == SEQ - 1) hfin[(size_t)gm * HID + gcol] = hn;
    }

    // ---- grid barrier (skip after last step) ----
    if (s != SEQ - 1) {
      __syncthreads();
      if (tid == 0) {
        __threadfence();  // release: my block's stores -> coherence point
        __hip_atomic_fetch_add(cnt, 1u, __ATOMIC_RELAXED, __HIP_MEMORY_SCOPE_AGENT);
        unsigned target = (unsigned)NBLK * (unsigned)(s + 1);
        while (__hip_atomic_load(cnt, __ATOMIC_RELAXED, __HIP_MEMORY_SCOPE_AGENT) < target)
          __builtin_amdgcn_s_sleep(2);
        __threadfence();  // acquire: invalidate stale L1/L2 lines
      }
      __syncthreads();
    }
  }
}

// ---------- host ----------
extern "C" void kernel_launch(void* const* d_in, const int* in_sizes, int n_in,
                              void* d_out, int out_size, void* d_ws, size_t ws_size,
                              hipStream_t stream) {
  const int* tok = (const int*)d_in[0];
  const float* hidden = (const float*)d_in[1];
  const float* emb = (const float*)d_in[2];
  const float* W_ir = (const float*)d_in[3];
  const float* b_ir = (const float*)d_in[4];
  const float* W_hr = (const float*)d_in[5];
  const float* b_hr = (const float*)d_in[6];
  const float* W_iu = (const float*)d_in[7];
  const float* b_iu = (const float*)d_in[8];
  const float* W_hu = (const float*)d_in[9];
  const float* b_hu = (const float*)d_in[10];
  const float* W_ic = (const float*)d_in[11];
  const float* b_ic = (const float*)d_in[12];
  const float* W_hc = (const float*)d_in[13];
  const float* b_hc = (const float*)d_in[14];
  const float* W_out = (const float*)d_in[15];
  const float* b_out = (const float*)d_in[16];

  char* p = (char*)d_ws;
  auto carve = [&](size_t n) {
    void* r = (void*)p;
    p += (n + 255) & ~(size_t)255;
    return r;
  };
  const size_t HH = (size_t)HID * HID;
  unsigned short* WiT_hi = (unsigned short*)carve(LAYERS * 3 * HH * 2);
  unsigned short* WiT_lo = (unsigned short*)carve(LAYERS * 3 * HH * 2);
  unsigned short* WhT_hi = (unsigned short*)carve(LAYERS * 3 * HH * 2);
  unsigned short* WhT_lo = (unsigned short*)carve(LAYERS * 3 * HH * 2);
  unsigned short* WoT = (unsigned short*)carve((size_t)HALFV * HID * 2);
  unsigned short* X0_hi = (unsigned short*)carve((size_t)MROWS * HID * 2);
  unsigned short* X0_lo = (unsigned short*)carve((size_t)MROWS * HID * 2);
  unsigned short* Xs_hi = (unsigned short*)carve((size_t)MROWS * HID * 2);
  unsigned short* Xs_lo = (unsigned short*)carve((size_t)MROWS * HID * 2);
  float* G = (float*)carve((size_t)3 * MROWS * HID * 4);
  unsigned short* h0_hi = (unsigned short*)carve((size_t)BATCH * HID * 2);
  unsigned short* h0_lo = (unsigned short*)carve((size_t)BATCH * HID * 2);
  float* hf32 = (float*)carve((size_t)2 * BATCH * HID * 4);
  unsigned* barrier_cnt = (unsigned*)carve(256);

  float* out = (float*)d_out;
  float* hfin_base = out + (size_t)MROWS * VOCAB;

  hipMemsetAsync(barrier_cnt, 0, 256, stream);
  trans12_k<<<dim3(48, 48, 12), dim3(32, 8), 0, stream>>>(
      W_ir, W_iu, W_ic, W_hr, W_hu, W_hc, WiT_hi, WiT_lo, WhT_hi, WhT_lo);
  embed_k<<<MROWS, 256, 0, stream>>>(tok, emb, X0_hi, X0_lo);

  for (int l = 0; l < LAYERS; ++l) {
    const unsigned short* Ahi = (l == 0) ? X0_hi : Xs_hi;
    const unsigned short* Alo = (l == 0) ? X0_lo : Xs_lo;
    const float* bi[3] = {b_ir + l * HID, b_iu + l * HID, b_ic + l * HID};
    for (int g = 0; g < 3; ++g) {
      gemm_split_k<<<dim3(16, 24), 256, 0, stream>>>(
          Ahi, Alo, WiT_hi + ((size_t)l * 3 + g) * HH, WiT_lo + ((size_t)l * 3 + g) * HH,
          bi[g], G + (size_t)g * MROWS * HID, HID, HID);
    }
    hinit_k<<<192, 256, 0, stream>>>(hidden + (size_t)l * BATCH * HID, h0_hi, h0_lo, hf32);
    gru_seq_k<<<NBLK, 512, 0, stream>>>(
        h0_hi, h0_lo, WhT_hi + (size_t)l * 3 * HH, WhT_lo + (size_t)l * 3 * HH,
        G, b_hr + l * HID, b_hu + l * HID, b_hc + l * HID,
        Xs_hi, Xs_lo, hf32, hfin_base + (size_t)l * BATCH * HID,
        barrier_cnt + l * 16);
  }

  for (int hf = 0; hf < 2; ++hf) {
    int coffs = hf * HALFV;
    trans_k<<<dim3(48, 500), dim3(32, 8), 0, stream>>>(W_out + coffs, VOCAB, WoT, HID);
    gemm_plain_k<<<dim3(16, 125), 256, 0, stream>>>(
        Xs_hi, WoT, b_out + coffs, out + coffs, HID, VOCAB);
  }
}